// Round 7
// baseline (19.770 us; speedup 1.0000x reference)
//
#include <hip/hip_runtime.h>
#include <hip/hip_bf16.h>
#include <hip/hip_fp16.h>

#define TLEN 4096
#define KTAPS 256
#define NT 18     // Toeplitz A tiles (K window = 288 = 18*16)
#define WCH 24    // B window chunks per block (384 floats = 256 halo + 128 out)

typedef __attribute__((ext_vector_type(8))) _Float16 f16x8;
typedef __attribute__((ext_vector_type(4))) unsigned int uint4v;
typedef __attribute__((ext_vector_type(16))) float f32x16;

// ---------------- Fused kernel: shfl-scan + tap table + LDS-staged Toeplitz MFMA ----
// Grid: (rows/32) x 32 blocks of 256 threads (4 waves). Block covers rows
// [rt*32,+32) x outputs [sg*128,+128); window t in [sg*128-256, sg*128+128).
// Phases: (1) burst-issue 12 float4 B loads  (2) wave0 shfl-based GL cumprod scan
// -> s[256]  (3) barrier; build reversed packed fp16 tap table wrevp from s
// (4) convert B -> fp16 frags in LDS  (5) barrier; 18-step MFMA, 1 acc/wave.
__global__ void __launch_bounds__(256, 5)
frac_conv_fused2(const float* __restrict__ x,
                 const float* __restrict__ loc,
                 const float* __restrict__ scale,
                 const float* __restrict__ eps,
                 float* __restrict__ out) {
    __shared__ __align__(16) float s[KTAPS];                  // 1 KB
    __shared__ unsigned int wrevp[320];                       // 1.25 KB
    __shared__ __align__(16) unsigned short Bf[WCH * 64 * 8]; // 24 KB

    const int tid  = threadIdx.x;
    const int wave = tid >> 6;
    const int lane = tid & 63;
    const int l5   = lane >> 5;
    const int ln   = lane & 31;

    // XCD swizzle: give each XCD a contiguous wgid chunk (8 row-tiles x 32 sg).
    int wgid = blockIdx.x;
    if ((gridDim.x & 7) == 0) {
        const int cpx = gridDim.x >> 3;
        wgid = (blockIdx.x & 7) * cpx + (blockIdx.x >> 3);
    }
    const int rt  = wgid >> 5;
    const int sg  = wgid & 31;
    const int bn0 = sg * 128;

    // ---- phase 1: burst-issue B window loads (32 rows x 384 floats, coalesced) ----
    const int r  = tid >> 3;          // row 0..31
    const int cg = tid & 7;           // 8 threads/row, 128B contiguous segments
    const float* __restrict__ xrow = x + (size_t)(rt * 32 + r) * TLEN;
    float4 v[12];
    #pragma unroll
    for (int jj = 0; jj < 12; ++jj) {
        const int w0 = cg * 4 + jj * 32;          // float offset in window [0,384)
        const int tg = bn0 - 256 + w0;            // global t of first elem
        v[jj] = (tg >= 0) ? *(const float4*)(xrow + tg) : make_float4(0.f, 0.f, 0.f, 0.f);
    }

    // ---- phase 2: barrier-free GL cumprod scan (wave 0 publishes) ----
    // lane l holds factors f(4l..4l+3); 6-step shfl_up product scan of group products.
    {
        const float alpha = loc[0] + log1pf(expf(scale[0])) * eps[0];
        const int j0 = 4 * lane;
        const float f0 = (j0 == 0) ? 1.0f : (((float)j0 - 1.0f - alpha) / (float)j0);
        const float f1 = (((float)j0 + 0.0f - alpha) / (float)(j0 + 1));
        const float f2 = (((float)j0 + 1.0f - alpha) / (float)(j0 + 2));
        const float f3 = (((float)j0 + 2.0f - alpha) / (float)(j0 + 3));
        const float p0 = f0, p1 = p0 * f1, p2 = p1 * f2, p3 = p2 * f3;
        float g = p3;
        #pragma unroll
        for (int dlt = 1; dlt < 64; dlt <<= 1) {
            const float t = __shfl_up(g, dlt, 64);
            if (lane >= dlt) g *= t;
        }
        float Sprev = __shfl_up(g, 1, 64);
        if (lane == 0) Sprev = 1.0f;
        if (wave == 0) {
            ((float4*)s)[lane] = make_float4(Sprev * p0, Sprev * p1, Sprev * p2, g);
        }
    }
    __syncthreads();

    // ---- phase 3: reversed packed fp16 tap table ----
    // wrev[j] = w[287-j] for 32<=j<=287 else 0; wrevp[j] = pack(wrev[j], wrev[j+1]).
    {
        const int j = tid;
        const float a = (j >= 32) ? s[287 - j] : 0.0f;
        const float b = (j >= 31) ? s[286 - j] : 0.0f;
        wrevp[j] = __builtin_bit_cast(unsigned int, __builtin_amdgcn_cvt_pkrtz(a, b));
        if (tid < 64) {
            const int j2 = 256 + tid;
            const float a2 = (j2 <= 287) ? s[287 - j2] : 0.0f;
            const float b2 = (j2 <= 286) ? s[286 - j2] : 0.0f;
            wrevp[j2] = __builtin_bit_cast(unsigned int, __builtin_amdgcn_cvt_pkrtz(a2, b2));
        }
    }

    // ---- phase 4: convert B to fp16 fragments in LDS ----
    {
        uint2* Bf2 = (uint2*)Bf;
        #pragma unroll
        for (int jj = 0; jj < 12; ++jj) {
            const int w0 = cg * 4 + jj * 32;
            const auto a = __builtin_amdgcn_cvt_pkrtz(v[jj].x, v[jj].y);
            const auto b = __builtin_amdgcn_cvt_pkrtz(v[jj].z, v[jj].w);
            const int c  = w0 >> 4;                // chunk
            const int h8 = (w0 >> 3) & 1;          // k-half
            const int e0 = w0 & 7;                 // 0 or 4
            const int uoff = (c * 64 + r + 32 * h8) * 8 + e0;  // ushort offset
            Bf2[uoff >> 2] = make_uint2(__builtin_bit_cast(unsigned int, a),
                                        __builtin_bit_cast(unsigned int, b));
        }
    }
    __syncthreads();

    // ---- phase 5: MFMA loop; A-fragments on the fly from wrevp ----
    const int n0  = bn0 + wave * 32;
    const int lcb = wave * 2;
    const f16x8* Bv = (const f16x8*)Bf;
    const int o0 = 31 - ln + 8 * l5;   // tap-table base for this lane

    auto LOADA = [&](int d) -> f16x8 {
        const int o = o0 + 16 * d;
        uint4v u;
        u[0] = wrevp[o];
        u[1] = wrevp[o + 2];
        u[2] = wrevp[o + 4];
        u[3] = wrevp[o + 6];
        return __builtin_bit_cast(f16x8, u);
    };

    f16x8 Afr[NT];
    f16x8 Bfr[NT];
    Bfr[0] = Bv[(lcb + 0) * 64 + lane];
    Bfr[1] = Bv[(lcb + 1) * 64 + lane];
    Bfr[2] = Bv[(lcb + 2) * 64 + lane];
    Bfr[3] = Bv[(lcb + 3) * 64 + lane];
    Afr[0] = LOADA(0);
    Afr[1] = LOADA(1);

    f32x16 acc = {0.f, 0.f, 0.f, 0.f, 0.f, 0.f, 0.f, 0.f,
                  0.f, 0.f, 0.f, 0.f, 0.f, 0.f, 0.f, 0.f};

    #pragma unroll
    for (int d = 0; d < NT; ++d) {
        if (d + 4 < NT) Bfr[d + 4] = Bv[(lcb + d + 4) * 64 + lane];
        if (d + 2 < NT) Afr[d + 2] = LOADA(d + 2);
        acc = __builtin_amdgcn_mfma_f32_32x32x16_f16(Afr[d], Bfr[d], acc, 0, 0, 0);
    }

    // D layout: col = lane&31 (row ln), m = (reg&3) + 8*(reg>>2) + 4*l5
    float* __restrict__ orow = out + (size_t)(rt * 32 + ln) * TLEN;
    #pragma unroll
    for (int g = 0; g < 4; ++g) {
        *(float4*)(orow + n0 + 8 * g + 4 * l5) =
            make_float4(acc[4 * g + 0], acc[4 * g + 1], acc[4 * g + 2], acc[4 * g + 3]);
    }
}

// ---------------- Fallback path (proven round-1 fp32 kernels) ----------------
__global__ void gl_coeff_kernel(const float* __restrict__ loc,
                                const float* __restrict__ scale,
                                const float* __restrict__ eps,
                                float* __restrict__ w_out) {
    __shared__ float s[KTAPS];
    const int j = threadIdx.x;
    const float alpha = loc[0] + log1pf(expf(scale[0])) * eps[0];
    float f = (j == 0) ? 1.0f : (((float)j - 1.0f - alpha) / (float)j);
    s[j] = f;
    __syncthreads();
    #pragma unroll
    for (int st = 1; st < KTAPS; st <<= 1) {
        float v = s[j];
        float p = (j >= st) ? s[j - st] : 1.0f;
        __syncthreads();
        s[j] = v * p;
        __syncthreads();
    }
    w_out[j] = s[j];
}

__global__ void __launch_bounds__(256)
frac_conv_kernel(const float* __restrict__ x,
                 const float* __restrict__ w,
                 float* __restrict__ out) {
    __shared__ __align__(16) float xs[KTAPS + TLEN];
    __shared__ __align__(16) float wl[KTAPS];
    const int row = blockIdx.x;
    const int tid = threadIdx.x;
    const float* __restrict__ xr = x + (size_t)row * TLEN;
    float* __restrict__ orow = out + (size_t)row * TLEN;
    if (tid < 64) ((float4*)xs)[tid] = make_float4(0.f, 0.f, 0.f, 0.f);
    float4* xs4w = (float4*)(xs + KTAPS);
    const float4* xr4 = (const float4*)xr;
    #pragma unroll
    for (int k = 0; k < 4; ++k) xs4w[tid + k * 256] = xr4[tid + k * 256];
    if (tid < 64) ((float4*)wl)[tid] = ((const float4*)w)[tid];
    __syncthreads();
    const float4* __restrict__ xsv = (const float4*)xs;
    float4 acc[4]; float4 lo[4], hi[4]; int n0[4];
    #pragma unroll
    for (int g = 0; g < 4; ++g) {
        n0[g] = (tid << 2) + (g << 10);
        acc[g] = make_float4(0.f, 0.f, 0.f, 0.f);
        const int c = n0[g] >> 2;
        hi[g] = xsv[64 + c];
        lo[g] = xsv[63 + c];
    }
    #pragma unroll 4
    for (int j = 0; j < KTAPS - 4; j += 4) {
        const float4 w4 = *(const float4*)(wl + j);
        #pragma unroll
        for (int g = 0; g < 4; ++g) {
            acc[g].x += w4.x*hi[g].x + w4.y*lo[g].w + w4.z*lo[g].z + w4.w*lo[g].y;
            acc[g].y += w4.x*hi[g].y + w4.y*hi[g].x + w4.z*lo[g].w + w4.w*lo[g].z;
            acc[g].z += w4.x*hi[g].z + w4.y*hi[g].y + w4.z*hi[g].x + w4.w*lo[g].w;
            acc[g].w += w4.x*hi[g].w + w4.y*hi[g].z + w4.z*hi[g].y + w4.w*hi[g].x;
            hi[g] = lo[g];
            lo[g] = xsv[64 + ((n0[g] - j - 8) >> 2)];
        }
    }
    {
        const float4 w4 = *(const float4*)(wl + (KTAPS - 4));
        #pragma unroll
        for (int g = 0; g < 4; ++g) {
            acc[g].x += w4.x*hi[g].x + w4.y*lo[g].w + w4.z*lo[g].z + w4.w*lo[g].y;
            acc[g].y += w4.x*hi[g].y + w4.y*hi[g].x + w4.z*lo[g].w + w4.w*lo[g].z;
            acc[g].z += w4.x*hi[g].z + w4.y*hi[g].y + w4.z*hi[g].x + w4.w*lo[g].w;
            acc[g].w += w4.x*hi[g].w + w4.y*hi[g].z + w4.z*hi[g].y + w4.w*hi[g].x;
        }
    }
    #pragma unroll
    for (int g = 0; g < 4; ++g) *(float4*)(orow + n0[g]) = acc[g];
}

extern "C" void kernel_launch(void* const* d_in, const int* in_sizes, int n_in,
                              void* d_out, int out_size, void* d_ws, size_t ws_size,
                              hipStream_t stream) {
    const float* x     = (const float*)d_in[0];
    const float* loc   = (const float*)d_in[1];
    const float* scale = (const float*)d_in[2];
    const float* eps   = (const float*)d_in[3];
    float* out = (float*)d_out;
    const int rows = in_sizes[0] / TLEN;  // 2048

    if ((rows % 32) == 0) {
        frac_conv_fused2<<<(rows / 32) * 32, 256, 0, stream>>>(x, loc, scale, eps, out);
    } else {
        float* w = (float*)d_ws;
        gl_coeff_kernel<<<1, 256, 0, stream>>>(loc, scale, eps, w);
        frac_conv_kernel<<<rows, 256, 0, stream>>>(x, w, out);
    }
}

// Round 8
// 18.901 us; speedup vs baseline: 1.0460x; 1.0460x over previous
//
#include <hip/hip_runtime.h>
#include <hip/hip_bf16.h>
#include <hip/hip_fp16.h>

#define TLEN 4096
#define KTAPS 256
#define NT 18     // Toeplitz A tiles (K window = 288 = 18*16)
#define WCH 48    // B window chunks per block (768 floats = 256 halo + 512 out)

typedef __attribute__((ext_vector_type(8))) _Float16 f16x8;
typedef __attribute__((ext_vector_type(4))) unsigned int uint4v;
typedef __attribute__((ext_vector_type(16))) float f32x16;

static __device__ __forceinline__ unsigned int pkf16(float a, float b) {
    return __builtin_bit_cast(unsigned int, __builtin_amdgcn_cvt_pkrtz(a, b));
}

// ---------------- Fused kernel: shfl-scan + reg tap table + LDS Toeplitz MFMA ------
// Grid: (rows/32) x 8 blocks of 512 threads (8 waves). Block covers rows
// [rt*32,+32) x outputs [sg*512,+512); window t in [sg*512-256, sg*512+512).
// Phases: (1) burst-issue 12 float4 B loads/thread  (2) wave0: shfl cumprod scan,
// write packed reversed fp16 tap table wrevp straight from registers
// (3) convert B -> fp16 frags in LDS  (4) ONE barrier  (5) 18-step MFMA, 2 acc/wave.
__global__ void __launch_bounds__(512, 4)
frac_conv_fused3(const float* __restrict__ x,
                 const float* __restrict__ loc,
                 const float* __restrict__ scale,
                 const float* __restrict__ eps,
                 float* __restrict__ out) {
    __shared__ unsigned int wrevp[320];                       // 1.25 KB
    __shared__ __align__(16) unsigned short Bf[WCH * 64 * 8]; // 48 KB

    const int tid  = threadIdx.x;
    const int wave = tid >> 6;
    const int lane = tid & 63;
    const int l5   = lane >> 5;
    const int ln   = lane & 31;

    // XCD swizzle: same-rt blocks (halo-sharing sg neighbors) land on one XCD.
    // bid -> xcd = bid&7 (HW round-robin); choose rt so all 8 sg of rt share xcd.
    int rt, sg;
    {
        const int bid = blockIdx.x;
        if (gridDim.x == 512) {
            const int xcd = bid & 7;
            const int j   = bid >> 3;          // 0..63
            rt = xcd * 8 + (j & 7);            // rts [8*xcd, 8*xcd+8) on this XCD
            sg = j >> 3;                       // 0..7
        } else {
            rt = bid >> 3;
            sg = bid & 7;
        }
    }
    const int bn0 = sg * 512;

    // ---- phase 1: burst-issue B window loads (32 rows x 768 floats, coalesced) ----
    const int r  = tid >> 4;          // row 0..31 (16 threads/row)
    const int cg = tid & 15;          // 256B contiguous segments per row
    const float* __restrict__ xrow = x + (size_t)(rt * 32 + r) * TLEN;
    float4 v[12];
    #pragma unroll
    for (int jj = 0; jj < 12; ++jj) {
        const int w0 = cg * 4 + jj * 64;          // float offset in window [0,768)
        const int tg = bn0 - 256 + w0;            // global t of first elem
        v[jj] = (tg >= 0) ? *(const float4*)(xrow + tg) : make_float4(0.f, 0.f, 0.f, 0.f);
    }

    // ---- phase 2: wave 0 computes GL cumprod scan, writes packed tap table ----
    // w_0=1, w_j = w_{j-1}*(j-1-alpha)/j. Lane l holds w[4l..4l+3] (+ w[4l-1]).
    // wrevp[j] = pack(wrev[j], wrev[j+1]), wrev[j] = w[287-j] (0 outside [0,255]).
    if (wave == 0) {
        const float alpha = loc[0] + log1pf(expf(scale[0])) * eps[0];
        const int j0 = 4 * lane;
        const float f0 = (j0 == 0) ? 1.0f : (((float)j0 - 1.0f - alpha) / (float)j0);
        const float f1 = (((float)j0 + 0.0f - alpha) / (float)(j0 + 1));
        const float f2 = (((float)j0 + 1.0f - alpha) / (float)(j0 + 2));
        const float f3 = (((float)j0 + 2.0f - alpha) / (float)(j0 + 3));
        const float p0 = f0, p1 = p0 * f1, p2 = p1 * f2, p3 = p2 * f3;
        float g = p3;
        #pragma unroll
        for (int dlt = 1; dlt < 64; dlt <<= 1) {
            const float t = __shfl_up(g, dlt, 64);
            if (lane >= dlt) g *= t;
        }
        float Sprev = __shfl_up(g, 1, 64);
        if (lane == 0) Sprev = 1.0f;
        const float q0 = Sprev * p0, q1 = Sprev * p1, q2 = Sprev * p2, q3 = g;
        const float wm1 = (lane == 0) ? 0.0f : Sprev;   // w[4l-1]
        // 4 packed words at j0b = 284-4*lane: (q3,q2),(q2,q1),(q1,q0),(q0,wm1)
        uint4v pk;
        pk[0] = pkf16(q3, q2);
        pk[1] = pkf16(q2, q1);
        pk[2] = pkf16(q1, q0);
        pk[3] = pkf16(q0, wm1);
        *(uint4v*)(wrevp + 284 - 4 * lane) = pk;        // 16B aligned
        if (lane == 63) wrevp[31] = pkf16(0.0f, q3);    // pack(w[256]=0, w[255])
        if (lane < 31)  wrevp[lane] = 0u;               // wrev[j]=0, j<31
        if (lane < 32)  wrevp[288 + lane] = 0u;         // wrev[j]=0, j>=288
    }

    // ---- phase 3: convert B to fp16 fragments in LDS ----
    {
        uint2* Bf2 = (uint2*)Bf;
        #pragma unroll
        for (int jj = 0; jj < 12; ++jj) {
            const int w0 = cg * 4 + jj * 64;
            const int c  = w0 >> 4;                // chunk
            const int h8 = (w0 >> 3) & 1;          // k-half
            const int e0 = w0 & 7;                 // 0 or 4
            const int uoff = (c * 64 + r + 32 * h8) * 8 + e0;  // ushort offset
            Bf2[uoff >> 2] = make_uint2(pkf16(v[jj].x, v[jj].y),
                                        pkf16(v[jj].z, v[jj].w));
        }
    }
    __syncthreads();   // the ONLY barrier

    // ---- phase 5: MFMA loop; A-fragments on the fly from wrevp ----
    const int n0  = bn0 + wave * 64;
    const int lcb = wave * 4;
    const f16x8* Bv = (const f16x8*)Bf;
    const int o0 = 31 - ln + 8 * l5;   // tap-table base for this lane

    auto LOADA = [&](int d) -> f16x8 {
        const int o = o0 + 16 * d;
        uint4v u;
        u[0] = wrevp[o];
        u[1] = wrevp[o + 2];
        u[2] = wrevp[o + 4];
        u[3] = wrevp[o + 6];
        return __builtin_bit_cast(f16x8, u);
    };

    f16x8 Afr[NT];
    f16x8 Bfr[NT + 2];
    Bfr[0] = Bv[(lcb + 0) * 64 + lane];
    Bfr[1] = Bv[(lcb + 1) * 64 + lane];
    Bfr[2] = Bv[(lcb + 2) * 64 + lane];
    Bfr[3] = Bv[(lcb + 3) * 64 + lane];
    Afr[0] = LOADA(0);
    Afr[1] = LOADA(1);

    f32x16 acc0 = {0.f, 0.f, 0.f, 0.f, 0.f, 0.f, 0.f, 0.f,
                   0.f, 0.f, 0.f, 0.f, 0.f, 0.f, 0.f, 0.f};
    f32x16 acc1 = acc0;

    #pragma unroll
    for (int d = 0; d < NT; ++d) {
        if (d + 4 < NT + 2) Bfr[d + 4] = Bv[(lcb + d + 4) * 64 + lane];
        if (d + 2 < NT)     Afr[d + 2] = LOADA(d + 2);
        acc0 = __builtin_amdgcn_mfma_f32_32x32x16_f16(Afr[d], Bfr[d],     acc0, 0, 0, 0);
        acc1 = __builtin_amdgcn_mfma_f32_32x32x16_f16(Afr[d], Bfr[d + 2], acc1, 0, 0, 0);
    }

    // D layout: col = lane&31 (row ln), m = (reg&3) + 8*(reg>>2) + 4*l5
    float* __restrict__ orow = out + (size_t)(rt * 32 + ln) * TLEN;
    #pragma unroll
    for (int g = 0; g < 4; ++g) {
        *(float4*)(orow + n0 + 8 * g + 4 * l5) =
            make_float4(acc0[4 * g + 0], acc0[4 * g + 1], acc0[4 * g + 2], acc0[4 * g + 3]);
        *(float4*)(orow + n0 + 32 + 8 * g + 4 * l5) =
            make_float4(acc1[4 * g + 0], acc1[4 * g + 1], acc1[4 * g + 2], acc1[4 * g + 3]);
    }
}

// ---------------- Fallback path (proven round-1 fp32 kernels) ----------------
__global__ void gl_coeff_kernel(const float* __restrict__ loc,
                                const float* __restrict__ scale,
                                const float* __restrict__ eps,
                                float* __restrict__ w_out) {
    __shared__ float s[KTAPS];
    const int j = threadIdx.x;
    const float alpha = loc[0] + log1pf(expf(scale[0])) * eps[0];
    float f = (j == 0) ? 1.0f : (((float)j - 1.0f - alpha) / (float)j);
    s[j] = f;
    __syncthreads();
    #pragma unroll
    for (int st = 1; st < KTAPS; st <<= 1) {
        float v = s[j];
        float p = (j >= st) ? s[j - st] : 1.0f;
        __syncthreads();
        s[j] = v * p;
        __syncthreads();
    }
    w_out[j] = s[j];
}

__global__ void __launch_bounds__(256)
frac_conv_kernel(const float* __restrict__ x,
                 const float* __restrict__ w,
                 float* __restrict__ out) {
    __shared__ __align__(16) float xs[KTAPS + TLEN];
    __shared__ __align__(16) float wl[KTAPS];
    const int row = blockIdx.x;
    const int tid = threadIdx.x;
    const float* __restrict__ xr = x + (size_t)row * TLEN;
    float* __restrict__ orow = out + (size_t)row * TLEN;
    if (tid < 64) ((float4*)xs)[tid] = make_float4(0.f, 0.f, 0.f, 0.f);
    float4* xs4w = (float4*)(xs + KTAPS);
    const float4* xr4 = (const float4*)xr;
    #pragma unroll
    for (int k = 0; k < 4; ++k) xs4w[tid + k * 256] = xr4[tid + k * 256];
    if (tid < 64) ((float4*)wl)[tid] = ((const float4*)w)[tid];
    __syncthreads();
    const float4* __restrict__ xsv = (const float4*)xs;
    float4 acc[4]; float4 lo[4], hi[4]; int n0[4];
    #pragma unroll
    for (int g = 0; g < 4; ++g) {
        n0[g] = (tid << 2) + (g << 10);
        acc[g] = make_float4(0.f, 0.f, 0.f, 0.f);
        const int c = n0[g] >> 2;
        hi[g] = xsv[64 + c];
        lo[g] = xsv[63 + c];
    }
    #pragma unroll 4
    for (int j = 0; j < KTAPS - 4; j += 4) {
        const float4 w4 = *(const float4*)(wl + j);
        #pragma unroll
        for (int g = 0; g < 4; ++g) {
            acc[g].x += w4.x*hi[g].x + w4.y*lo[g].w + w4.z*lo[g].z + w4.w*lo[g].y;
            acc[g].y += w4.x*hi[g].y + w4.y*hi[g].x + w4.z*lo[g].w + w4.w*lo[g].z;
            acc[g].z += w4.x*hi[g].z + w4.y*hi[g].y + w4.z*hi[g].x + w4.w*lo[g].w;
            acc[g].w += w4.x*hi[g].w + w4.y*hi[g].z + w4.z*hi[g].y + w4.w*hi[g].x;
            hi[g] = lo[g];
            lo[g] = xsv[64 + ((n0[g] - j - 8) >> 2)];
        }
    }
    {
        const float4 w4 = *(const float4*)(wl + (KTAPS - 4));
        #pragma unroll
        for (int g = 0; g < 4; ++g) {
            acc[g].x += w4.x*hi[g].x + w4.y*lo[g].w + w4.z*lo[g].z + w4.w*lo[g].y;
            acc[g].y += w4.x*hi[g].y + w4.y*hi[g].x + w4.z*lo[g].w + w4.w*lo[g].z;
            acc[g].z += w4.x*hi[g].z + w4.y*hi[g].y + w4.z*hi[g].x + w4.w*lo[g].w;
            acc[g].w += w4.x*hi[g].w + w4.y*hi[g].z + w4.z*hi[g].y + w4.w*hi[g].x;
        }
    }
    #pragma unroll
    for (int g = 0; g < 4; ++g) *(float4*)(orow + n0[g]) = acc[g];
}

extern "C" void kernel_launch(void* const* d_in, const int* in_sizes, int n_in,
                              void* d_out, int out_size, void* d_ws, size_t ws_size,
                              hipStream_t stream) {
    const float* x     = (const float*)d_in[0];
    const float* loc   = (const float*)d_in[1];
    const float* scale = (const float*)d_in[2];
    const float* eps   = (const float*)d_in[3];
    float* out = (float*)d_out;
    const int rows = in_sizes[0] / TLEN;  // 2048

    if ((rows % 32) == 0) {
        frac_conv_fused3<<<(rows / 32) * 8, 512, 0, stream>>>(x, loc, scale, eps, out);
    } else {
        float* w = (float*)d_ws;
        gl_coeff_kernel<<<1, 256, 0, stream>>>(loc, scale, eps, w);
        frac_conv_kernel<<<rows, 256, 0, stream>>>(x, w, out);
    }
}